// Round 7
// baseline (47.646 us; speedup 1.0000x reference)
//
#include <hip/hip_runtime.h>

// Top1Gate via bf16x3-split MFMA GEMM, v7.
// logits = x @ W^T [16384,64]; idx = argmax; scores = max; mask = one-hot.
// Output flat (float32): [idx 16384][scores 16384][mask 16384*64]
//
// v7 vs v6: wconv kernel ELIMINATED. Gate reads w fp32 directly (same bytes:
// hi+lo bf16 == fp32) and splits in VALU after the counted vmcnt wait. Load
// counts per sub-iter unchanged -> R6's verified vmcnt schedule kept intact.
// Single kernel: no serial pre-pass, no inter-kernel gap.

typedef float  f32x4  __attribute__((ext_vector_type(4)));
typedef short  bf16x8 __attribute__((ext_vector_type(8)));

constexpr int BATCH = 16384;
constexpr int DM    = 2048;
constexpr int NE    = 64;
constexpr int BM    = 32;          // rows per block
constexpr int NT    = 256;         // 4 waves = 4 k-quarters
// chunk = 16 rows x 128 k = 8 KB; 32 chunks: c -> (h = c&1 row-half, kblk 0..15)

__device__ __forceinline__ void split_bf16(float f, unsigned short& hi, unsigned short& lo) {
    unsigned u  = __float_as_uint(f);
    unsigned h  = (u + 0x8000u) >> 16;           // round-half-up to bf16
    float    hf = __uint_as_float(h << 16);
    unsigned l  = __float_as_uint(f - hf) >> 16; // truncate residual
    hi = (unsigned short)h;
    lo = (unsigned short)l;
}

struct BSet { bf16x8 v[8]; };   // [term=2(hi,lo)][tile=4] for one 32-k step

__global__ __launch_bounds__(NT, 2)
void gate_kernel(const float* __restrict__ x,
                 const float* __restrict__ w,
                 float* __restrict__ out) {
    __shared__ alignas(16) float xs[4][16 * 32 * 4];   // 4-slot ring x 8 KB
    __shared__ float lg[BM][NE + 1];                   // stride 65: conflict-free
    __shared__ int   s_idx[BM];

    const int t     = threadIdx.x;
    const int lane  = t & 63;
    const int q     = t >> 6;                 // k-quarter 0..3
    const int row0  = blockIdx.x * BM;
    const int phase = (blockIdx.x & 15) << 1; // EVEN de-phase: preserves kblk pairing

    f32x4 acc[2][4];
    #pragma unroll
    for (int h = 0; h < 2; ++h)
        #pragma unroll
        for (int n = 0; n < 4; ++n) acc[h][n] = (f32x4){0.f, 0.f, 0.f, 0.f};

    auto kbOf = [&](int c) { return ((c + phase) >> 1) & 15; };

    // stage logical chunk c into ring slot b: 16 rows x 128 k = 512 f4, 2/thread
    auto stage_x = [&](int c, int b) {
        const int h = c & 1;
        const float* xg = x + (size_t)(row0 + h * 16) * DM + kbOf(c) * 128;
        #pragma unroll
        for (int i = 0; i < 2; ++i) {
            int d    = i * NT + t;            // 0..511 linear dest f4 slot
            int r    = d >> 5;                // row 0..15
            int sdst = d & 31;
            int ssrc = sdst ^ ((r & 7) << 2); // pre-swizzled source (linear LDS dest)
            __builtin_amdgcn_global_load_lds(
                (const __attribute__((address_space(1))) void*)(xg + (size_t)r * DM + ssrc * 4),
                (__attribute__((address_space(3))) void*)(&xs[b][d * 4]),
                16, 0, 0);
        }
    };

    // raw W loads for logical chunk c's kblk (k-step = quarter q): 8 loads, fp32.
    // lane covers expert = n*16 + (lane&15), k = ks*32 + (lane>>4)*8 + 0..7
    auto load_raw = [&](int c, f32x4* R) {
        int ks = kbOf(c) * 4 + q;
        const float* wp = w + (size_t)(lane & 15) * DM + ks * 32 + ((lane >> 4) << 3);
        #pragma unroll
        for (int n = 0; n < 4; ++n) {
            R[n * 2 + 0] = *(const f32x4*)(wp + (size_t)n * 16 * DM);
            R[n * 2 + 1] = *(const f32x4*)(wp + (size_t)n * 16 * DM + 4);
        }
    };

    // split raw fp32 W into bf16 hi/lo fragment set (bit-identical to old wconv)
    auto mksplit = [&](const f32x4* R, BSet& S) {
        #pragma unroll
        for (int n = 0; n < 4; ++n) {
            bf16x8 hi, lo;
            #pragma unroll
            for (int j = 0; j < 8; ++j) {
                float f = (j < 4) ? R[n * 2][j] : R[n * 2 + 1][j - 4];
                unsigned short h, l;
                split_bf16(f, h, l);
                hi[j] = (short)h;
                lo[j] = (short)l;
            }
            S.v[n]     = hi;
            S.v[4 + n] = lo;
        }
    };

    // compute chunk in slot b (row-half hh literal), this wave's 32-k quarter
    auto compute = [&](int b, int hh, const BSet& B) {
        const int rA = lane & 15;
        const int s0 = q * 8 + ((lane >> 4) << 1);
        const int xr = (rA & 7) << 2;
        f32x4 a0 = *(const f32x4*)&xs[b][(rA * 32 + ((s0 + 0) ^ xr)) * 4];
        f32x4 a1 = *(const f32x4*)&xs[b][(rA * 32 + ((s0 + 1) ^ xr)) * 4];
        bf16x8 ahi, alo;
        #pragma unroll
        for (int j = 0; j < 8; ++j) {
            float f = (j < 4) ? a0[j] : a1[j - 4];
            unsigned short h, l;
            split_bf16(f, h, l);
            ahi[j] = (short)h;
            alo[j] = (short)l;
        }
        #pragma unroll
        for (int n = 0; n < 4; ++n) {
            acc[hh][n] = __builtin_amdgcn_mfma_f32_16x16x32_bf16(ahi, B.v[0 + n], acc[hh][n], 0, 0, 0);
            acc[hh][n] = __builtin_amdgcn_mfma_f32_16x16x32_bf16(ahi, B.v[4 + n], acc[hh][n], 0, 0, 0);
            acc[hh][n] = __builtin_amdgcn_mfma_f32_16x16x32_bf16(alo, B.v[0 + n], acc[hh][n], 0, 0, 0);
        }
    };

    f32x4 rawA[8], rawB[8];
    BSet  S;

    // prologue: queue = [rawA(0):8, X0:2, X1:2, X2:2] = 14 -> wait(4) drains rawA0, X0
    load_raw(0, rawA);
    stage_x(0, 0);
    stage_x(1, 1);
    stage_x(2, 2);
    asm volatile("s_waitcnt vmcnt(4)" ::: "memory");
    __builtin_amdgcn_sched_barrier(0);
    __builtin_amdgcn_s_barrier();

    // steady state: identical issue counts to v6 (even sub-iter 10, odd 2);
    // wait(12) drains current raw set + the X chunk for the NEXT sub-iter,
    // keeps 2 HBM x-chunks + next raw set in flight. One barrier per chunk.
    #pragma unroll 1
    for (int c = 0; c < 28; c += 4) {
        load_raw(c + 2, rawB);
        stage_x(c + 3, (c + 3) & 3);
        asm volatile("s_waitcnt vmcnt(12)" ::: "memory");
        __builtin_amdgcn_sched_barrier(0);
        mksplit(rawA, S);
        compute((c + 0) & 3, 0, S);
        __builtin_amdgcn_s_barrier();

        stage_x(c + 4, (c + 4) & 3);
        asm volatile("s_waitcnt vmcnt(12)" ::: "memory");
        __builtin_amdgcn_sched_barrier(0);
        compute((c + 1) & 3, 1, S);
        __builtin_amdgcn_s_barrier();

        load_raw(c + 4, rawA);
        stage_x(c + 5, (c + 5) & 3);
        asm volatile("s_waitcnt vmcnt(12)" ::: "memory");
        __builtin_amdgcn_sched_barrier(0);
        mksplit(rawB, S);
        compute((c + 2) & 3, 0, S);
        __builtin_amdgcn_s_barrier();

        stage_x(c + 6, (c + 6) & 3);
        asm volatile("s_waitcnt vmcnt(12)" ::: "memory");
        __builtin_amdgcn_sched_barrier(0);
        compute((c + 3) & 3, 1, S);
        __builtin_amdgcn_s_barrier();
    }

    // tail: exact counts, no junk loads.
    load_raw(30, rawB);
    stage_x(31, 3);
    asm volatile("s_waitcnt vmcnt(12)" ::: "memory");   // drains rawA(28), X29
    __builtin_amdgcn_sched_barrier(0);
    mksplit(rawA, S);
    compute(0, 0, S);                                   // chunk 28
    __builtin_amdgcn_s_barrier();

    compute(1, 1, S);                                   // chunk 29
    __builtin_amdgcn_s_barrier();

    asm volatile("s_waitcnt vmcnt(2)" ::: "memory");    // drain X30, rawB; leave X31
    __builtin_amdgcn_sched_barrier(0);
    mksplit(rawB, S);
    compute(2, 0, S);                                   // chunk 30
    __builtin_amdgcn_s_barrier();

    asm volatile("s_waitcnt vmcnt(0)" ::: "memory");
    __builtin_amdgcn_sched_barrier(0);
    compute(3, 1, S);                                   // chunk 31
    __syncthreads();

    // 4-way k-quarter reduce into lg (deterministic serial order)
    // C/D layout: row_local = (lane>>4)*4 + j, col = n*16 + (lane&15)
    const int rb = (lane >> 4) << 2;
    const int cb = lane & 15;
    if (q == 0) {
        #pragma unroll
        for (int h = 0; h < 2; ++h)
            #pragma unroll
            for (int n = 0; n < 4; ++n)
                #pragma unroll
                for (int j = 0; j < 4; ++j)
                    lg[h * 16 + rb + j][n * 16 + cb] = acc[h][n][j];
    }
    __syncthreads();
    if (q == 1) {
        #pragma unroll
        for (int h = 0; h < 2; ++h)
            #pragma unroll
            for (int n = 0; n < 4; ++n)
                #pragma unroll
                for (int j = 0; j < 4; ++j)
                    lg[h * 16 + rb + j][n * 16 + cb] += acc[h][n][j];
    }
    __syncthreads();
    if (q == 2) {
        #pragma unroll
        for (int h = 0; h < 2; ++h)
            #pragma unroll
            for (int n = 0; n < 4; ++n)
                #pragma unroll
                for (int j = 0; j < 4; ++j)
                    lg[h * 16 + rb + j][n * 16 + cb] += acc[h][n][j];
    }
    __syncthreads();
    if (q == 3) {
        #pragma unroll
        for (int h = 0; h < 2; ++h)
            #pragma unroll
            for (int n = 0; n < 4; ++n)
                #pragma unroll
                for (int j = 0; j < 4; ++j)
                    lg[h * 16 + rb + j][n * 16 + cb] += acc[h][n][j];
    }
    __syncthreads();

    if (t < BM) {
        float m  = lg[t][0];
        int   mi = 0;
        #pragma unroll
        for (int e = 1; e < NE; ++e) {
            float v = lg[t][e];
            if (v > m) { m = v; mi = e; }
        }
        s_idx[t] = mi;
        out[row0 + t]         = (float)mi;
        out[BATCH + row0 + t] = m;
    }
    __syncthreads();

    // one-hot mask: 32 rows x 64 = 2048 floats; 8/thread, coalesced f32x4
    float* mask = out + 2 * (size_t)BATCH;
    int r  = t >> 3;
    int c0 = (t & 7) * 8;
    int mi = s_idx[r];
    #pragma unroll
    for (int i = 0; i < 2; ++i) {
        f32x4 v;
        #pragma unroll
        for (int j = 0; j < 4; ++j) v[j] = (c0 + i * 4 + j == mi) ? 1.0f : 0.0f;
        *(f32x4*)&mask[(size_t)(row0 + r) * NE + c0 + i * 4] = v;
    }
}

extern "C" void kernel_launch(void* const* d_in, const int* in_sizes, int n_in,
                              void* d_out, int out_size, void* d_ws, size_t ws_size,
                              hipStream_t stream) {
    const float* x = (const float*)d_in[0];
    const float* w = (const float*)d_in[1];
    float* out     = (float*)d_out;

    gate_kernel<<<dim3(BATCH / BM), dim3(NT), 0, stream>>>(x, w, out);
}